// Round 8
// baseline (114.043 us; speedup 1.0000x reference)
//
#include <hip/hip_runtime.h>

typedef float f32x4 __attribute__((ext_vector_type(4)));

// Problem dims (fixed by reference): bs=4, L=512, H=768, C=48
#define H_DIM 768
#define C_DIM 48
#define NROWS 2048          // bs * L
#define TWO_H 1536

// pgemm geometry
#define BM 32               // rows per block
#define BK 32               // k per LDS step
#define KSLICE 96           // k per k-slice block
#define NSTEP (KSLICE / BK) // 3
#define KS 8                // split-k factor
#define RGS (NROWS / BM)    // 64 rowgroups
#define LDA 33
#define LDB 33
#define PART_ELEMS (KS * NROWS * 96)   // 1572864 floats (6.3 MB)

// ---------------------------------------------------------------------------
// Kernel 1 (fused): W-transpose-on-stage + split-k GEMM + fan-in reduction.
// grid = 64 rowgroups x 8 k-slices = 512 blocks (2/CU), block = 256 threads.
// part[kg][row][c] = sum_{k in slice} hs[row][k] * Wcol(c)[k]
// Last-arriving block per rowgroup (atomic ticket) sums the 8 partials in
// fixed order and writes proj[half][row][cl] — deterministic output.
// ---------------------------------------------------------------------------
__global__ __launch_bounds__(256) void pgemm_kernel(const float* __restrict__ hs,
                                                    const float* __restrict__ W,
                                                    float* __restrict__ part,
                                                    float* __restrict__ proj,
                                                    unsigned int* __restrict__ ctr) {
    __shared__ float A_lds[2][BM][LDA];   // 8.4 KB
    __shared__ float B_lds[2][96][LDB];   // 25.3 KB
    __shared__ unsigned int s_ticket;

    const int t     = threadIdx.x;
    const int kg    = blockIdx.x & (KS - 1);   // k-slice 0..7
    const int rg    = blockIdx.x >> 3;         // rowgroup 0..63
    const int row0  = rg * BM;
    const int kbase = kg * KSLICE;

    // staging roles: A: one f32x4 per thread; B: 3 f32x4 per thread (on-the-fly transpose)
    const int a_row = t >> 3;                  // 0..31
    const int a_kf4 = t & 7;                   // 0..7

    const f32x4* __restrict__ hs4 = reinterpret_cast<const f32x4*>(hs);

    f32x4 a_reg, b_reg[3];

    // ---- load step 0 into regs ----
    {
        const int k0 = kbase;
        a_reg = hs4[(size_t)(row0 + a_row) * (H_DIM / 4) + (k0 >> 2) + a_kf4];
        #pragma unroll
        for (int q = 0; q < 3; ++q) {
            const int idx  = q * 256 + t;      // 0..767
            const int c    = idx >> 3;         // 0..95
            const int kf4  = idx & 7;
            const int half = c / C_DIM;
            const int cc   = c - half * C_DIM;
            b_reg[q] = *reinterpret_cast<const f32x4*>(
                W + (size_t)cc * TWO_H + (size_t)half * H_DIM + k0 + kf4 * 4);
        }
    }
    // ---- write step 0 to LDS buf 0 ----
    {
        *reinterpret_cast<f32x4*>(&A_lds[0][a_row][a_kf4 * 4]) = a_reg;
        #pragma unroll
        for (int q = 0; q < 3; ++q) {
            const int idx = q * 256 + t;
            const int c   = idx >> 3;
            const int kf4 = idx & 7;
            *reinterpret_cast<f32x4*>(&B_lds[0][c][kf4 * 4]) = b_reg[q];
        }
    }

    // compute tile: 4 rows x 3 cols per thread
    const int rq = t >> 5;                     // 0..7  -> rows rq*4..+3
    const int cq = t & 31;                     // 0..31 -> cols cq*3..+2

    float acc[4][3];
    #pragma unroll
    for (int ri = 0; ri < 4; ++ri)
        #pragma unroll
        for (int cj = 0; cj < 3; ++cj) acc[ri][cj] = 0.f;

    for (int s = 0; s < NSTEP; ++s) {
        __syncthreads();

        if (s + 1 < NSTEP) {                   // prefetch next step into regs
            const int k0 = kbase + (s + 1) * BK;
            a_reg = hs4[(size_t)(row0 + a_row) * (H_DIM / 4) + (k0 >> 2) + a_kf4];
            #pragma unroll
            for (int q = 0; q < 3; ++q) {
                const int idx  = q * 256 + t;
                const int c    = idx >> 3;
                const int kf4  = idx & 7;
                const int half = c / C_DIM;
                const int cc   = c - half * C_DIM;
                b_reg[q] = *reinterpret_cast<const f32x4*>(
                    W + (size_t)cc * TWO_H + (size_t)half * H_DIM + k0 + kf4 * 4);
            }
        }

        const int buf = s & 1;
        #pragma unroll
        for (int kk4 = 0; kk4 < BK / 4; ++kk4) {
            f32x4 a[4], b[3];
            #pragma unroll
            for (int ri = 0; ri < 4; ++ri)
                a[ri] = *reinterpret_cast<const f32x4*>(&A_lds[buf][rq * 4 + ri][kk4 * 4]);
            #pragma unroll
            for (int cj = 0; cj < 3; ++cj)
                b[cj] = *reinterpret_cast<const f32x4*>(&B_lds[buf][cq * 3 + cj][kk4 * 4]);
            #pragma unroll
            for (int ri = 0; ri < 4; ++ri)
                #pragma unroll
                for (int cj = 0; cj < 3; ++cj) {
                    acc[ri][cj] += a[ri].x * b[cj].x;
                    acc[ri][cj] += a[ri].y * b[cj].y;
                    acc[ri][cj] += a[ri].z * b[cj].z;
                    acc[ri][cj] += a[ri].w * b[cj].w;
                }
        }

        __syncthreads();

        if (s + 1 < NSTEP) {                   // write prefetched regs to other buffer
            const int buf2 = (s + 1) & 1;
            *reinterpret_cast<f32x4*>(&A_lds[buf2][a_row][a_kf4 * 4]) = a_reg;
            #pragma unroll
            for (int q = 0; q < 3; ++q) {
                const int idx = q * 256 + t;
                const int c   = idx >> 3;
                const int kf4 = idx & 7;
                *reinterpret_cast<f32x4*>(&B_lds[buf2][c][kf4 * 4]) = b_reg[q];
            }
        }
    }

    // ---- write this k-slice's partial slab ----
    float* __restrict__ pslab = part + (size_t)kg * (NROWS * 96);
    #pragma unroll
    for (int ri = 0; ri < 4; ++ri) {
        const int row = row0 + rq * 4 + ri;
        #pragma unroll
        for (int cj = 0; cj < 3; ++cj)
            pslab[(size_t)row * 96 + cq * 3 + cj] = acc[ri][cj];
    }

    // ---- fan-in: last k-slice block of this rowgroup reduces ----
    __threadfence();                           // release partial stores (device scope)
    __syncthreads();
    if (t == 0) s_ticket = atomicAdd(&ctr[rg], 1u);
    __syncthreads();
    if (s_ticket == KS - 1) {
        __threadfence();                       // acquire: see other XCDs' partials
        const f32x4* __restrict__ part4 = reinterpret_cast<const f32x4*>(part);
        f32x4* __restrict__ proj4 = reinterpret_cast<f32x4*>(proj);
        #pragma unroll
        for (int q = 0; q < 3; ++q) {
            const int p   = q * 256 + t;       // 0..767
            const int row = p / 24;
            const int c4  = p % 24;
            f32x4 v = part4[(size_t)(row0 + row) * 24 + c4];
            #pragma unroll
            for (int g = 1; g < KS; ++g)
                v += part4[(size_t)g * (NROWS * 24) + (size_t)(row0 + row) * 24 + c4];
            const int half = c4 / 12;
            const int cl4  = c4 % 12;
            proj4[(size_t)half * (NROWS * 12) + (size_t)(row0 + row) * 12 + cl4] = v;
        }
    }
}

// ---------------------------------------------------------------------------
// Kernel 2: out[b,i,j,c] = proj_i[b,i,c] + proj_j[b,j,c] + bias[c]
// R4 version (best measured): one block per (b,i), 2048 x 256.
// ---------------------------------------------------------------------------
__global__ __launch_bounds__(256) void bcast_kernel(const float* __restrict__ proj,
                                                    const float* __restrict__ bias,
                                                    float* __restrict__ out) {
    const int gi = blockIdx.x;          // b*512 + i
    const int b  = gi >> 9;

    __shared__ f32x4 rowi[C_DIM / 4];   // proj_i[b,i,:] + bias  (12 f32x4)

    const int t = threadIdx.x;
    if (t < C_DIM / 4) {
        f32x4 pi = reinterpret_cast<const f32x4*>(proj + (size_t)gi * C_DIM)[t];
        f32x4 bb = reinterpret_cast<const f32x4*>(bias)[t];
        rowi[t] = pi + bb;
    }
    __syncthreads();

    const f32x4* __restrict__ pj =
        reinterpret_cast<const f32x4*>(proj + (size_t)NROWS * C_DIM
                                            + (size_t)b * 512 * C_DIM);
    f32x4* __restrict__ o =
        reinterpret_cast<f32x4*>(out) + (size_t)gi * (512 * C_DIM / 4);

    constexpr int SLAB_F4 = 512 * C_DIM / 4;   // 6144
    #pragma unroll
    for (int it = 0; it < SLAB_F4 / 256; ++it) {
        const int p  = it * 256 + t;
        const int c4 = p % 12;
        o[p] = pj[p] + rowi[c4];
    }
}

extern "C" void kernel_launch(void* const* d_in, const int* in_sizes, int n_in,
                              void* d_out, int out_size, void* d_ws, size_t ws_size,
                              hipStream_t stream) {
    const float* hs   = (const float*)d_in[0];   // (4, 512, 768) f32
    const float* W    = (const float*)d_in[1];   // (48, 1536)    f32
    const float* bias = (const float*)d_in[2];   // (48,)         f32
    float* out  = (float*)d_out;                 // (4,512,512,48) f32
    float* proj = (float*)d_ws;                  // 2*2048*48 floats = 786 KB

    // Scratch in the d_out tail (consumed before bcast overwrites it):
    //   [... out ... | part (6.29 MB) | ctr (256 B)]
    unsigned int* ctr  = (unsigned int*)(out + (size_t)out_size - RGS);
    float*        part = out + (size_t)out_size - RGS - PART_ELEMS;

    hipMemsetAsync(ctr, 0, RGS * sizeof(unsigned int), stream);
    pgemm_kernel<<<dim3(RGS * KS), 256, 0, stream>>>(hs, W, part, proj, ctr);
    bcast_kernel<<<dim3(NROWS), 256, 0, stream>>>(proj, bias, out);
}

// Round 9
// 49.682 us; speedup vs baseline: 2.2954x; 2.2954x over previous
//
#include <hip/hip_runtime.h>

typedef float f32x4 __attribute__((ext_vector_type(4)));

// Problem dims (fixed by reference): bs=4, L=512, H=768, C=48
#define H_DIM 768
#define C_DIM 48
#define NROWS 2048          // bs * L
#define TWO_H 1536

// pgemm geometry (R7 proven: BM=64, KS=8, 256 blocks, 1/CU)
#define BM 64
#define BK 32
#define KSLICE 96
#define NSTEP (KSLICE / BK)   // 3
#define KS 8
#define LDA 33                // 32 + 1 pad
#define LDB 33
#define PART_ELEMS (KS * NROWS * 96)   // 1572864 floats (6.29 MB)

// ---------------------------------------------------------------------------
// Kernel 1: split-k tiled GEMM, B staged DIRECTLY from W with on-the-fly
// transpose (no separate wtrans kernel, no Wt round-trip).
// part[kg][row][c] = sum_{k in kg-slice} hs[row][k] * Wcol(c)[k]
//   Wcol(c)[k] = W[c][k] (c<48) ; W[c-48][768+k] (c>=48)
// grid = 32 rowgroups x 8 k-slices = 256 blocks (1/CU), block = 256 threads.
// Inner loop is pure LDS + FMA; global loads only in the double-buffered
// staging (prefetched into regs, written to LDS after the compute barrier).
// ---------------------------------------------------------------------------
__global__ __launch_bounds__(256) void pgemm_kernel(const float* __restrict__ hs,
                                                    const float* __restrict__ W,
                                                    float* __restrict__ part) {
    __shared__ float A_lds[2][BM][LDA];   // 2 x 8.4 KB
    __shared__ float B_lds[2][96][LDB];   // 2 x 12.7 KB

    const int t     = threadIdx.x;
    const int kg    = blockIdx.x & 7;     // k-slice 0..7
    const int rg    = blockIdx.x >> 3;    // rowgroup 0..31
    const int row0  = rg * BM;
    const int kbase = kg * KSLICE;

    const int r4 = t >> 4;                // 0..15 (4 rows each)
    const int c6 = t & 15;                // 0..15 (6 cols each)

    const f32x4* __restrict__ hs4 = reinterpret_cast<const f32x4*>(hs);

    // Staging roles. A: rows a_row, a_row+32; B: 3 f32x4/thread from W rows.
    const int a_row = t >> 3;             // 0..31
    const int a_kf4 = t & 7;              // 0..7

    f32x4 a_reg[2], b_reg[3];

    // ---- load step 0 into regs ----
    {
        const int k0 = kbase;
        #pragma unroll
        for (int i = 0; i < 2; ++i)
            a_reg[i] = hs4[(size_t)(row0 + a_row + i * 32) * (H_DIM / 4) + (k0 >> 2) + a_kf4];
        #pragma unroll
        for (int q = 0; q < 3; ++q) {
            const int idx  = q * 256 + t;  // 0..767
            const int c    = idx >> 3;     // 0..95
            const int kf4  = idx & 7;      // 0..7
            const int half = c / C_DIM;
            const int cc   = c - half * C_DIM;
            b_reg[q] = *reinterpret_cast<const f32x4*>(
                W + (size_t)cc * TWO_H + (size_t)half * H_DIM + k0 + kf4 * 4);
        }
    }
    // ---- write step 0 to LDS buf 0 ----
    {
        #pragma unroll
        for (int i = 0; i < 2; ++i)
            *reinterpret_cast<f32x4*>(&A_lds[0][a_row + i * 32][a_kf4 * 4]) = a_reg[i];
        #pragma unroll
        for (int q = 0; q < 3; ++q) {
            const int idx = q * 256 + t;
            const int c   = idx >> 3;
            const int kf4 = idx & 7;
            *reinterpret_cast<f32x4*>(&B_lds[0][c][kf4 * 4]) = b_reg[q];
        }
    }

    float acc[4][6];
    #pragma unroll
    for (int ri = 0; ri < 4; ++ri)
        #pragma unroll
        for (int j = 0; j < 6; ++j) acc[ri][j] = 0.f;

    for (int s = 0; s < NSTEP; ++s) {
        __syncthreads();

        // Prefetch step s+1 into regs (overlaps with compute below).
        if (s + 1 < NSTEP) {
            const int k0 = kbase + (s + 1) * BK;
            #pragma unroll
            for (int i = 0; i < 2; ++i)
                a_reg[i] = hs4[(size_t)(row0 + a_row + i * 32) * (H_DIM / 4) + (k0 >> 2) + a_kf4];
            #pragma unroll
            for (int q = 0; q < 3; ++q) {
                const int idx  = q * 256 + t;
                const int c    = idx >> 3;
                const int kf4  = idx & 7;
                const int half = c / C_DIM;
                const int cc   = c - half * C_DIM;
                b_reg[q] = *reinterpret_cast<const f32x4*>(
                    W + (size_t)cc * TWO_H + (size_t)half * H_DIM + k0 + kf4 * 4);
            }
        }

        // Compute step s from LDS.
        const int buf = s & 1;
        #pragma unroll
        for (int kk4 = 0; kk4 < BK / 4; ++kk4) {
            f32x4 a[4], b[6];
            #pragma unroll
            for (int ri = 0; ri < 4; ++ri)
                a[ri] = *reinterpret_cast<const f32x4*>(&A_lds[buf][r4 * 4 + ri][kk4 * 4]);
            #pragma unroll
            for (int j = 0; j < 6; ++j)
                b[j] = *reinterpret_cast<const f32x4*>(&B_lds[buf][c6 * 6 + j][kk4 * 4]);
            #pragma unroll
            for (int ri = 0; ri < 4; ++ri)
                #pragma unroll
                for (int j = 0; j < 6; ++j) {
                    acc[ri][j] += a[ri].x * b[j].x;
                    acc[ri][j] += a[ri].y * b[j].y;
                    acc[ri][j] += a[ri].z * b[j].z;
                    acc[ri][j] += a[ri].w * b[j].w;
                }
        }

        __syncthreads();

        // Write prefetched regs into the other LDS buffer.
        if (s + 1 < NSTEP) {
            const int buf2 = (s + 1) & 1;
            #pragma unroll
            for (int i = 0; i < 2; ++i)
                *reinterpret_cast<f32x4*>(&A_lds[buf2][a_row + i * 32][a_kf4 * 4]) = a_reg[i];
            #pragma unroll
            for (int q = 0; q < 3; ++q) {
                const int idx = q * 256 + t;
                const int c   = idx >> 3;
                const int kf4 = idx & 7;
                *reinterpret_cast<f32x4*>(&B_lds[buf2][c][kf4 * 4]) = b_reg[q];
            }
        }
    }

    // Epilogue: write the 4x6 tile to this k-slice's partial slab.
    float* __restrict__ pslab = part + (size_t)kg * (NROWS * 96);
    #pragma unroll
    for (int ri = 0; ri < 4; ++ri) {
        const int row = row0 + r4 * 4 + ri;
        #pragma unroll
        for (int j = 0; j < 6; ++j)
            pslab[(size_t)row * 96 + c6 * 6 + j] = acc[ri][j];
    }
}

// ---------------------------------------------------------------------------
// Kernel 1b: reduce 8 k-slice partials -> proj[half][row][cl]
// 49152 f32x4 outputs; grid = 192 x 256, one f32x4 per thread.
// ---------------------------------------------------------------------------
__global__ __launch_bounds__(256) void preduce_kernel(const float* __restrict__ part,
                                                      float* __restrict__ proj) {
    const int p = blockIdx.x * 256 + threadIdx.x;     // 0..49151
    const f32x4* __restrict__ part4 = reinterpret_cast<const f32x4*>(part);

    f32x4 v = part4[p];
    #pragma unroll
    for (int g = 1; g < 8; ++g)
        v += part4[(size_t)g * (NROWS * 96 / 4) + p];

    const int row  = p / 24;
    const int c4   = p % 24;
    const int half = c4 / 12;
    const int cl4  = c4 % 12;
    reinterpret_cast<f32x4*>(proj)[(size_t)half * (NROWS * 12) + (size_t)row * 12 + cl4] = v;
}

// ---------------------------------------------------------------------------
// Kernel 2: out[b,i,j,c] = proj_i[b,i,c] + proj_j[b,j,c] + bias[c]
// R4 version (best measured): one block per (b,i), 2048 x 256.
// ---------------------------------------------------------------------------
__global__ __launch_bounds__(256) void bcast_kernel(const float* __restrict__ proj,
                                                    const float* __restrict__ bias,
                                                    float* __restrict__ out) {
    const int gi = blockIdx.x;          // b*512 + i
    const int b  = gi >> 9;

    __shared__ f32x4 rowi[C_DIM / 4];   // proj_i[b,i,:] + bias  (12 f32x4)

    const int t = threadIdx.x;
    if (t < C_DIM / 4) {
        f32x4 pi = reinterpret_cast<const f32x4*>(proj + (size_t)gi * C_DIM)[t];
        f32x4 bb = reinterpret_cast<const f32x4*>(bias)[t];
        rowi[t] = pi + bb;
    }
    __syncthreads();

    const f32x4* __restrict__ pj =
        reinterpret_cast<const f32x4*>(proj + (size_t)NROWS * C_DIM
                                            + (size_t)b * 512 * C_DIM);
    f32x4* __restrict__ o =
        reinterpret_cast<f32x4*>(out) + (size_t)gi * (512 * C_DIM / 4);

    constexpr int SLAB_F4 = 512 * C_DIM / 4;   // 6144
    #pragma unroll
    for (int it = 0; it < SLAB_F4 / 256; ++it) {
        const int p  = it * 256 + t;
        const int c4 = p % 12;
        o[p] = pj[p] + rowi[c4];
    }
}

extern "C" void kernel_launch(void* const* d_in, const int* in_sizes, int n_in,
                              void* d_out, int out_size, void* d_ws, size_t ws_size,
                              hipStream_t stream) {
    const float* hs   = (const float*)d_in[0];   // (4, 512, 768) f32
    const float* W    = (const float*)d_in[1];   // (48, 1536)    f32
    const float* bias = (const float*)d_in[2];   // (48,)         f32
    float* out  = (float*)d_out;                 // (4,512,512,48) f32
    float* proj = (float*)d_ws;                  // 2*2048*48 floats = 786 KB

    // part lives in the d_out tail (consumed by preduce before bcast
    // overwrites it). No counters, no memsets, no atomics.
    float* part = out + (size_t)out_size - PART_ELEMS;

    pgemm_kernel<<<dim3(256), 256, 0, stream>>>(hs, W, part);
    preduce_kernel<<<dim3(192), 256, 0, stream>>>(part, proj);
    bcast_kernel<<<dim3(NROWS), 256, 0, stream>>>(proj, bias, out);
}